// Round 7
// baseline (251.237 us; speedup 1.0000x reference)
//
#include <hip/hip_runtime.h>

#define CH 64
#define CHUNK 4096
#define BSHIFT 8          // 256 nodes per bucket
#define NBUCK 196         // ceil(50000 / 256); requires N < 65536 (16-bit packing)

__device__ __forceinline__ unsigned short f2bf_rne(float f) {
    unsigned int u = __float_as_uint(f);
    u += 0x7fffu + ((u >> 16) & 1u);   // round to nearest even
    return (unsigned short)(u >> 16);
}
__device__ __forceinline__ float bf_lo(unsigned int q) {  // low bf16 of packed pair
    return __uint_as_float(q << 16);
}
__device__ __forceinline__ float bf_hi(unsigned int q) {  // high bf16
    return __uint_as_float(q & 0xffff0000u);
}
__device__ __forceinline__ unsigned int pack2bf(float lo, float hi) {
    return (unsigned int)f2bf_rne(lo) | ((unsigned int)f2bf_rne(hi) << 16);
}

// ---------- pass 1: per-bucket histogram (dst >> 8) ----------
__global__ __launch_bounds__(256) void bucket_hist_kernel(
        const int* __restrict__ dst, int* __restrict__ bucket_cnt, int E) {
    __shared__ int hist[256];
    int tid = threadIdx.x;
    int e0 = blockIdx.x * CHUNK;
    int total = min(CHUNK, E - e0);
    hist[tid] = 0;
    __syncthreads();
    for (int i = tid; i < total; i += 256)
        atomicAdd(&hist[dst[e0 + i] >> BSHIFT], 1);
    __syncthreads();
    if (tid < NBUCK && hist[tid]) atomicAdd(&bucket_cnt[tid], hist[tid]);
}

// ---------- pass 2: scan bucket counts -> base & cursor ----------
__global__ __launch_bounds__(256) void bucket_scan_kernel(
        const int* __restrict__ cnt, int* __restrict__ base,
        int* __restrict__ cursor, int* __restrict__ rowptr, int N, int E) {
    __shared__ int sc[256];
    int tid = threadIdx.x;
    int c = (tid < NBUCK) ? cnt[tid] : 0;
    sc[tid] = c;
    __syncthreads();
    for (int off = 1; off < 256; off <<= 1) {
        int v = (tid >= off) ? sc[tid - off] : 0;
        __syncthreads();
        sc[tid] += v;
        __syncthreads();
    }
    if (tid < NBUCK) { base[tid] = sc[tid] - c; cursor[tid] = sc[tid] - c; }
    if (tid == NBUCK - 1) base[NBUCK] = sc[tid];
    if (tid == 0) rowptr[N] = E;
}

// ---------- pass 3: bin edges into bucket regions (coalesced flush) ----------
// pairs packed as (dst<<16)|src  (N < 65536)
__global__ __launch_bounds__(256) void bin_kernel(
        const int* __restrict__ src, const int* __restrict__ dst,
        int* __restrict__ cursor, unsigned int* __restrict__ pairs, int E) {
    __shared__ unsigned int stage[CHUNK];                 // 16 KB
    __shared__ int hist[256], sc[256], lbase[256], lcur[256], gbase[256];
    int tid = threadIdx.x;
    int e0 = blockIdx.x * CHUNK;
    int total = min(CHUNK, E - e0);
    hist[tid] = 0;
    __syncthreads();
    for (int i = tid; i < total; i += 256)
        atomicAdd(&hist[dst[e0 + i] >> BSHIFT], 1);
    __syncthreads();
    sc[tid] = hist[tid];
    __syncthreads();
    for (int off = 1; off < 256; off <<= 1) {
        int v = (tid >= off) ? sc[tid - off] : 0;
        __syncthreads();
        sc[tid] += v;
        __syncthreads();
    }
    lbase[tid] = sc[tid] - hist[tid];
    lcur[tid]  = sc[tid] - hist[tid];
    if (tid < NBUCK && hist[tid] > 0) gbase[tid] = atomicAdd(&cursor[tid], hist[tid]);
    __syncthreads();
    for (int i = tid; i < total; i += 256) {
        unsigned int s = (unsigned int)src[e0 + i];
        unsigned int d = (unsigned int)dst[e0 + i];
        int pos = atomicAdd(&lcur[d >> BSHIFT], 1);
        stage[pos] = (d << 16) | s;
    }
    __syncthreads();
    for (int i = tid; i < total; i += 256) {
        unsigned int p = stage[i];
        int b = (int)(p >> 24);                          // dst >> 8
        pairs[gbase[b] + (i - lbase[b])] = p;            // coalesced per segment
    }
}

// ---------- pass 4: per-bucket counting sort -> csr, rowptr, dinv ----------
__global__ __launch_bounds__(256) void bucket_sort_kernel(
        const unsigned int* __restrict__ pairs, const int* __restrict__ base,
        int* __restrict__ csr, int* __restrict__ rowptr,
        float* __restrict__ dinv, int N) {
    __shared__ int cntl[256], sc[256], cur[256];
    int tid = threadIdx.x;
    int b = blockIdx.x;
    int pbase = base[b], pend = base[b + 1];
    int cnt = pend - pbase;
    cntl[tid] = 0;
    __syncthreads();
    for (int i = tid; i < cnt; i += 256)
        atomicAdd(&cntl[(pairs[pbase + i] >> 16) & 255u], 1);
    __syncthreads();
    sc[tid] = cntl[tid];
    __syncthreads();
    for (int off = 1; off < 256; off <<= 1) {
        int v = (tid >= off) ? sc[tid - off] : 0;
        __syncthreads();
        sc[tid] += v;
        __syncthreads();
    }
    int excl = sc[tid] - cntl[tid];
    cur[tid] = excl;
    int v = (b << BSHIFT) + tid;
    if (v < N) {
        rowptr[v] = pbase + excl;
        dinv[v] = rsqrtf((float)(cntl[tid] + 1));  // deg = indeg + 1 (self loop)
    }
    __syncthreads();
    for (int i = tid; i < cnt; i += 256) {
        unsigned int p = pairs[pbase + i];
        int pos = atomicAdd(&cur[(p >> 16) & 255u], 1);
        csr[pbase + pos] = (int)(p & 0xffffu);           // src
    }
}

// ---------- GEMM (f32 input) + dinv prescale: G = bf16( dinv ⊙ (X @ W) ) ----------
template <int K>
__global__ __launch_bounds__(256) void gemm_f32_kernel(
        const float* __restrict__ X, const float* __restrict__ W,
        const float* __restrict__ dinv, unsigned short* __restrict__ G, int N) {
    constexpr int KC  = 64;
    constexpr int XLD = KC + 4;           // padded row stride (floats)
    __shared__ float Xs[64 * XLD];        // 17408 B
    __shared__ float Wls[KC * CH];        // 16384 B
    int tid = threadIdx.x;
    int tx  = tid & 15;                   // output col group (4 cols)
    int ty  = tid >> 4;                   // output row group (4 rows)
    int row_tile = blockIdx.x * 64;
    int r0 = ty * 4;
    float acc[4][4] = {{0.f}};

    for (int kc = 0; kc < K; kc += KC) {
        __syncthreads();
#pragma unroll
        for (int t = 0; t < 4; ++t) {
            int idx = tid + t * 256;      // 0..1023
            int row = idx >> 4;
            int k4  = idx & 15;
            int grow = row_tile + row;
            const float4* xs = (const float4*)(X + (size_t)min(grow, N - 1) * K + kc);
            *(float4*)&Xs[row * XLD + 4 * k4] = xs[k4];
        }
#pragma unroll
        for (int t = 0; t < 4; ++t) {
            int idx = tid + t * 256;
            *(float4*)&Wls[idx * 4] = ((const float4*)(W + (size_t)kc * CH))[idx];
        }
        __syncthreads();
#pragma unroll
        for (int kk = 0; kk < KC; kk += 4) {
            float xr[4][4], wr[4][4];
#pragma unroll
            for (int i = 0; i < 4; ++i) {
                float4 v = *(const float4*)&Xs[(r0 + i) * XLD + kk];
                xr[i][0] = v.x; xr[i][1] = v.y; xr[i][2] = v.z; xr[i][3] = v.w;
            }
#pragma unroll
            for (int j = 0; j < 4; ++j) {
                float4 v = *(const float4*)&Wls[(kk + j) * CH + 4 * tx];
                wr[j][0] = v.x; wr[j][1] = v.y; wr[j][2] = v.z; wr[j][3] = v.w;
            }
#pragma unroll
            for (int i = 0; i < 4; ++i)
#pragma unroll
                for (int j = 0; j < 4; ++j)
#pragma unroll
                    for (int c = 0; c < 4; ++c)
                        acc[i][c] = fmaf(xr[i][j], wr[j][c], acc[i][c]);
        }
    }
#pragma unroll
    for (int i = 0; i < 4; ++i) {
        int r = row_tile + r0 + i;
        if (r < N) {
            float d = dinv[r];
            ushort4 o;
            o.x = f2bf_rne(acc[i][0] * d);
            o.y = f2bf_rne(acc[i][1] * d);
            o.z = f2bf_rne(acc[i][2] * d);
            o.w = f2bf_rne(acc[i][3] * d);
            ((ushort4*)G)[(size_t)r * 16 + tx] = o;
        }
    }
}

// ---------- GEMM (bf16 input, K=64) + dinv prescale -> bf16 ----------
__global__ __launch_bounds__(256) void gemm_bf16_kernel(
        const unsigned short* __restrict__ Xbf, const float* __restrict__ W,
        const float* __restrict__ dinv, unsigned short* __restrict__ G, int N) {
    constexpr int XLDU = 36;              // uints per row (32 + pad), 16B-aligned rows
    __shared__ unsigned int Xs[64 * XLDU];  // 9216 B
    __shared__ float Wls[64 * CH];          // 16384 B
    int tid = threadIdx.x;
    int tx  = tid & 15;
    int ty  = tid >> 4;
    int row_tile = blockIdx.x * 64;
    int r0 = ty * 4;
    float acc[4][4] = {{0.f}};

#pragma unroll
    for (int t = 0; t < 2; ++t) {
        int idx = tid + t * 256;          // 0..511 : 64 rows x 8 uint4
        int row = idx >> 3;
        int k4  = idx & 7;
        int grow = row_tile + row;
        uint4 v = ((const uint4*)Xbf)[(size_t)min(grow, N - 1) * 8 + k4];
        *(uint4*)&Xs[row * XLDU + 4 * k4] = v;
    }
#pragma unroll
    for (int t = 0; t < 4; ++t) {
        int idx = tid + t * 256;
        *(float4*)&Wls[idx * 4] = ((const float4*)W)[idx];
    }
    __syncthreads();
#pragma unroll
    for (int kk = 0; kk < 64; kk += 4) {
        float xr[4][4], wr[4][4];
#pragma unroll
        for (int i = 0; i < 4; ++i) {
            uint2 q = *(const uint2*)&Xs[(r0 + i) * XLDU + (kk >> 1)];
            xr[i][0] = bf_lo(q.x); xr[i][1] = bf_hi(q.x);
            xr[i][2] = bf_lo(q.y); xr[i][3] = bf_hi(q.y);
        }
#pragma unroll
        for (int j = 0; j < 4; ++j) {
            float4 v = *(const float4*)&Wls[(kk + j) * CH + 4 * tx];
            wr[j][0] = v.x; wr[j][1] = v.y; wr[j][2] = v.z; wr[j][3] = v.w;
        }
#pragma unroll
        for (int i = 0; i < 4; ++i)
#pragma unroll
            for (int j = 0; j < 4; ++j)
#pragma unroll
                for (int c = 0; c < 4; ++c)
                    acc[i][c] = fmaf(xr[i][j], wr[j][c], acc[i][c]);
    }
#pragma unroll
    for (int i = 0; i < 4; ++i) {
        int r = row_tile + r0 + i;
        if (r < N) {
            float d = dinv[r];
            ushort4 o;
            o.x = f2bf_rne(acc[i][0] * d);
            o.y = f2bf_rne(acc[i][1] * d);
            o.z = f2bf_rne(acc[i][2] * d);
            o.w = f2bf_rne(acc[i][3] * d);
            ((ushort4*)G)[(size_t)r * 16 + tx] = o;
        }
    }
}

// ---------- gather aggregation: out[v] = dinv[v]*(g[v] + sum_{u -> v} g[u]) ----------
// 8 nodes per wave, 8 lanes per node (lane cl covers channels cl*8..cl*8+7 as
// one uint4 of bf16). No cross-lane reduction needed; loop bound = wave max deg.
template <bool F32OUT>
__global__ __launch_bounds__(256) void aggregate_kernel(
        const unsigned short* __restrict__ G, const int* __restrict__ rowptr,
        const int* __restrict__ csr, const float* __restrict__ dinv,
        void* __restrict__ Out, int N, int E, int relu) {
    int lane = threadIdx.x & 63;
    int w = (blockIdx.x * 256 + threadIdx.x) >> 6;  // global wave id
    int grp = lane >> 3;                            // node slot in wave
    int cl  = lane & 7;                             // channel block (8 bf16 = 16B)
    int v = w * 8 + grp;
    bool valid = v < N;
    int vc = valid ? v : N - 1;
    int beg = rowptr[vc];
    int cnt = valid ? rowptr[vc + 1] - beg : 0;
    int mx = cnt;
    mx = max(mx, __shfl_xor(mx, 8));
    mx = max(mx, __shfl_xor(mx, 16));
    mx = max(mx, __shfl_xor(mx, 32));

    const uint4* __restrict__ G4 = (const uint4*)G;  // 8 uint4 per row
    float a0 = 0.f, a1 = 0.f, a2 = 0.f, a3 = 0.f;
    float a4 = 0.f, a5 = 0.f, a6 = 0.f, a7 = 0.f;
#pragma unroll 2
    for (int it = 0; it < mx; ++it) {
        int eg = min(beg + it, E - 1);
        bool ok = it < cnt;
        int u = ok ? csr[eg] : 0;
        float s = ok ? 1.f : 0.f;
        uint4 q = G4[(size_t)u * 8 + cl];
        a0 = fmaf(bf_lo(q.x), s, a0); a1 = fmaf(bf_hi(q.x), s, a1);
        a2 = fmaf(bf_lo(q.y), s, a2); a3 = fmaf(bf_hi(q.y), s, a3);
        a4 = fmaf(bf_lo(q.z), s, a4); a5 = fmaf(bf_hi(q.z), s, a5);
        a6 = fmaf(bf_lo(q.w), s, a6); a7 = fmaf(bf_hi(q.w), s, a7);
    }
    if (valid) {
        uint4 q = G4[(size_t)v * 8 + cl];   // self loop term
        float d = dinv[v];
        float o0 = (a0 + bf_lo(q.x)) * d, o1 = (a1 + bf_hi(q.x)) * d;
        float o2 = (a2 + bf_lo(q.y)) * d, o3 = (a3 + bf_hi(q.y)) * d;
        float o4 = (a4 + bf_lo(q.z)) * d, o5 = (a5 + bf_hi(q.z)) * d;
        float o6 = (a6 + bf_lo(q.w)) * d, o7 = (a7 + bf_hi(q.w)) * d;
        if (relu) {
            o0 = fmaxf(o0, 0.f); o1 = fmaxf(o1, 0.f); o2 = fmaxf(o2, 0.f);
            o3 = fmaxf(o3, 0.f); o4 = fmaxf(o4, 0.f); o5 = fmaxf(o5, 0.f);
            o6 = fmaxf(o6, 0.f); o7 = fmaxf(o7, 0.f);
        }
        if (F32OUT) {
            float4 w0 = {o0, o1, o2, o3}, w1 = {o4, o5, o6, o7};
            ((float4*)Out)[(size_t)v * 16 + cl * 2]     = w0;
            ((float4*)Out)[(size_t)v * 16 + cl * 2 + 1] = w1;
        } else {
            uint4 p;
            p.x = pack2bf(o0, o1); p.y = pack2bf(o2, o3);
            p.z = pack2bf(o4, o5); p.w = pack2bf(o6, o7);
            ((uint4*)Out)[(size_t)v * 8 + cl] = p;
        }
    }
}

// ---------- graph boundaries via binary search (batch is sorted) ----------
__global__ void gptr_kernel(const int* __restrict__ batch, int* __restrict__ gptr,
                            int N, int NG) {
    int g = blockIdx.x * blockDim.x + threadIdx.x;
    if (g > NG) return;
    if (g == NG) { gptr[NG] = N; return; }
    int lo = 0, hi = N;
    while (lo < hi) {
        int mid = (lo + hi) >> 1;
        if (batch[mid] < g) lo = mid + 1; else hi = mid;
    }
    gptr[g] = lo;  // first index with batch[i] >= g
}

// ---------- fused mean-pool + linear head ----------
__global__ __launch_bounds__(64) void pool_head_kernel(
        const float* __restrict__ H, const int* __restrict__ gptr,
        const float* __restrict__ Wl, const float* __restrict__ bl,
        float* __restrict__ out, int NG) {
    int g = blockIdx.x;
    int lane = threadIdx.x;  // 64 = CH
    int s = gptr[g], e = gptr[g + 1];
    float acc = 0.f;
    for (int v = s; v < e; ++v) acc += H[(size_t)v * CH + lane];
    float c = (float)(e - s);
    float mean = (c > 0.f) ? acc / c : 0.f;
    for (int o = 0; o < 10; ++o) {
        float t = mean * Wl[lane * 10 + o];
        for (int off = 32; off > 0; off >>= 1) t += __shfl_down(t, off);
        if (lane == 0) out[g * 10 + o] = t + bl[o];
    }
}

extern "C" void kernel_launch(void* const* d_in, const int* in_sizes, int n_in,
                              void* d_out, int out_size, void* d_ws, size_t ws_size,
                              hipStream_t stream) {
    const float* x     = (const float*)d_in[0];
    const int*   ei    = (const int*)d_in[1];
    const int*   batch = (const int*)d_in[2];
    const float* W1    = (const float*)d_in[3];
    const float* W2    = (const float*)d_in[4];
    const float* W3    = (const float*)d_in[5];
    const float* Wl    = (const float*)d_in[6];
    const float* bl    = (const float*)d_in[7];
    float* out = (float*)d_out;

    const int N  = in_sizes[0] / 128;  // 50000 (< 65536: 16-bit packing assumption)
    const int E  = in_sizes[1] / 2;    // 1250000
    const int NG = out_size / 10;      // 500

    const int* src = ei;
    const int* dst = ei + E;

    // workspace carve-out (256B aligned)
    char* ws = (char*)d_ws;
    size_t off = 0;
    auto alloc = [&](size_t bytes) -> void* {
        void* p = ws + off;
        off += bytes;
        off = (off + 255) & ~(size_t)255;
        return p;
    };
    int*   bucket_cnt    = (int*)alloc((size_t)NBUCK * 4);
    int*   bucket_base   = (int*)alloc((size_t)(NBUCK + 1) * 4);
    int*   bucket_cursor = (int*)alloc((size_t)NBUCK * 4);
    int*   csr    = (int*)alloc((size_t)(E + 64) * 4);
    int*   rowptr = (int*)alloc((size_t)(N + 1) * 4);
    float* dinv   = (float*)alloc((size_t)N * 4);
    int*   gptr   = (int*)alloc((size_t)(NG + 1) * 4);
    unsigned short* Gbf = (unsigned short*)alloc((size_t)N * CH * 2);  // 6.4MB
    unsigned short* Hbf = (unsigned short*)alloc((size_t)N * CH * 2);  // 6.4MB
    float* hbuf   = (float*)alloc((size_t)N * CH * 4);   // f32 h3; aliases pairs (5MB<12.8MB)
    unsigned int* pairs = (unsigned int*)hbuf;  // CSR build done before agg3 writes hbuf

    hipMemsetAsync(bucket_cnt, 0, (size_t)NBUCK * 4, stream);

    int cb = (E + CHUNK - 1) / CHUNK;  // 306
    int ab = ((N + 7) / 8 + 3) / 4;    // aggregate: 8 nodes/wave, 4 waves/block
    int gb = (N + 63) / 64;            // gemm: 64-row tiles

    bucket_hist_kernel<<<cb, 256, 0, stream>>>(dst, bucket_cnt, E);
    bucket_scan_kernel<<<1, 256, 0, stream>>>(bucket_cnt, bucket_base, bucket_cursor,
                                              rowptr, N, E);
    bin_kernel<<<cb, 256, 0, stream>>>(src, dst, bucket_cursor, pairs, E);
    bucket_sort_kernel<<<NBUCK, 256, 0, stream>>>(pairs, bucket_base, csr, rowptr, dinv, N);
    gptr_kernel<<<(NG + 512) / 512, 512, 0, stream>>>(batch, gptr, N, NG);

    // layer 1: 128 -> 64, relu
    gemm_f32_kernel<128><<<gb, 256, 0, stream>>>(x, W1, dinv, Gbf, N);
    aggregate_kernel<false><<<ab, 256, 0, stream>>>(Gbf, rowptr, csr, dinv, Hbf, N, E, 1);
    // layer 2: 64 -> 64, relu
    gemm_bf16_kernel<<<gb, 256, 0, stream>>>(Hbf, W2, dinv, Gbf, N);
    aggregate_kernel<false><<<ab, 256, 0, stream>>>(Gbf, rowptr, csr, dinv, Hbf, N, E, 1);
    // layer 3: 64 -> 64, no relu
    gemm_bf16_kernel<<<gb, 256, 0, stream>>>(Hbf, W3, dinv, Gbf, N);
    aggregate_kernel<true><<<ab, 256, 0, stream>>>(Gbf, rowptr, csr, dinv, hbuf, N, E, 0);

    // mean pool + linear head
    pool_head_kernel<<<NG, 64, 0, stream>>>(hbuf, gptr, Wl, bl, out, NG);
}